// Round 3
// baseline (315.890 us; speedup 1.0000x reference)
//
#include <hip/hip_runtime.h>
#include <hip/hip_bf16.h>

// Problem constants
#define NN 50000
#define DD 128
#define FF 16

typedef __hip_bfloat16 bf;
typedef __attribute__((ext_vector_type(8))) short short8;
typedef __attribute__((ext_vector_type(4))) float f32x4;

// Output element offsets (f32 elements, concatenated in reference return order)
#define O_H0  0            // h_lst[0][0], h_lst[0][1]  : 2 * N*128
#define O_H1  12800000     // h_lst[1][0], h_lst[1][1]  : 2 * N*128
#define O_FIN 25600000     // fin[0], fin[1]            : 2 * N*16
#define O_C0  27200000     // c_lst[0][0], c_lst[0][1]  : 2 * N*128
#define O_C1  40000000     // c_lst[1][0], c_lst[1][1]  : 2 * N*128
// total = 52800000 f32 elements

__device__ __forceinline__ bf f2b(float v) { return __float2bfloat16(v); }
__device__ __forceinline__ short f2bs(float v) {
  union { bf h; short s; } u; u.h = __float2bfloat16(v); return u.s;
}
__device__ __forceinline__ float frcp(float x) { return __builtin_amdgcn_rcpf(x); }
__device__ __forceinline__ float sigm(float x) { return frcp(1.f + __expf(-x)); }
__device__ __forceinline__ float tanhr(float x) {
  float e = __expf(2.f * x);
  return (e - 1.f) * frcp(e + 1.f);
}

// ---------------------------------------------------------------------------
// prep: W1 (f32) -> W1T[t][g3][d][k] (bf16), linW (f32) -> linWT[t][j][k] (bf16),
// bias1[t][g3][d] (f32). Gates used: g3 0->i(0), 1->cand(2), 2->o(3); f-gate dead
// because c_prev == 0 (reference re-zeroes state each layer).
// ---------------------------------------------------------------------------
__global__ void prep_kernel(const float* __restrict__ W1, const float* __restrict__ linW,
                            const float* __restrict__ b, const float* __restrict__ cbl,
                            bf* __restrict__ W1T, bf* __restrict__ linWT,
                            float* __restrict__ bias1) {
  int idx = blockIdx.x * 256 + threadIdx.x;
  const int G[3] = {0, 2, 3};
  if (idx < 98304) {                       // W1T: 2*3*128*128
    int t = idx / 49152, r = idx % 49152;
    int g3 = r / 16384, r2 = r % 16384;
    int d = r2 / 128, k = r2 % 128;
    int g = G[g3];
    W1T[idx] = f2b(W1[((g * 2 + t) * 128 + k) * 128 + d]);
  } else if (idx < 102400) {               // linWT: 2*16*128
    int i = idx - 98304;
    int t = i / 2048, r = i % 2048;
    int j = r / 128, k = r % 128;
    linWT[i] = f2b(linW[(t * 128 + k) * 16 + j]);
  } else if (idx < 103168) {               // bias1: 2*3*128 (layer-1 effective bias)
    int i = idx - 102400;
    int t = i / 384, r = i % 384;
    int g3 = r / 128, d = r % 128;
    int g = G[g3];
    // b[l=1][g][t][d] + convbl[l=1]: station (t=0) gets e=1 (g->s);
    // grid (t=1) gets e=0 (s->g) + e=2 (g->g)  [SAGE with h=0 -> its bias]
    float v = b[((4 + g) * 2 + t) * 128 + d];
    if (t == 0) v += cbl[((4 + g) * 3 + 1) * 128 + d];
    else        v += cbl[((4 + g) * 3 + 0) * 128 + d] + cbl[((4 + g) * 3 + 2) * 128 + d];
    bias1[i] = v;
  }
}

// ---------------------------------------------------------------------------
// layer 0: x[N,16] (f32) @ W0[g,t][16,128] (f32) + bias -> LSTM elementwise.
// Writes h_lst[0] (relu'd) and c_lst[0], both f32. Pure f32 VALU compute.
// ---------------------------------------------------------------------------
__global__ __launch_bounds__(256) void layer0_kernel(
    const float* __restrict__ x_st, const float* __restrict__ x_gr,
    const float* __restrict__ W0, const float* __restrict__ b,
    const float* __restrict__ cbl, float* __restrict__ out) {
  const int t = blockIdx.y;
  const int n0 = blockIdx.x * 32;
  const float* __restrict__ x = t ? x_gr : x_st;
  __shared__ float sw[3][16][128];
  __shared__ float sx[32][16];
  __shared__ float sb[3][128];
  const int tid = threadIdx.x;
  const int G[3] = {0, 2, 3};
  for (int i = tid; i < 6144; i += 256) {
    int g3 = i >> 11, k = (i >> 7) & 15, d = i & 127;
    sw[g3][k][d] = W0[((G[g3] * 2 + t) * 16 + k) * 128 + d];
  }
  for (int i = tid; i < 512; i += 256) {
    int nl = i >> 4, k = i & 15;
    int n = n0 + nl;
    sx[nl][k] = (n < NN) ? x[n * 16 + k] : 0.f;
  }
  for (int i = tid; i < 384; i += 256) {
    int g3 = i >> 7, d = i & 127, g = G[g3];
    float v = b[(g * 2 + t) * 128 + d];
    v += (t == 0) ? cbl[(g * 3 + 1) * 128 + d]
                  : cbl[(g * 3 + 0) * 128 + d] + cbl[(g * 3 + 2) * 128 + d];
    sb[g3][d] = v;
  }
  __syncthreads();
  const int d = tid & 127, half = tid >> 7;
  float w0r[16], w2r[16], w3r[16];
#pragma unroll
  for (int k = 0; k < 16; ++k) {
    w0r[k] = sw[0][k][d]; w2r[k] = sw[1][k][d]; w3r[k] = sw[2][k][d];
  }
  const float b0 = sb[0][d], b2v = sb[1][d], b3 = sb[2][d];
  for (int j = 0; j < 16; ++j) {
    int nl = half * 16 + j;
    int n = n0 + nl;
    float a0 = b0, a2 = b2v, a3 = b3;
#pragma unroll
    for (int k = 0; k < 16; ++k) {
      float xv = sx[nl][k];
      a0 += xv * w0r[k]; a2 += xv * w2r[k]; a3 += xv * w3r[k];
    }
    float ii = sigm(a0), tt = tanhr(a2), oo = sigm(a3);
    float c0 = ii * tt;
    float h = oo * tanhr(c0);
    float x1 = h > 0.f ? h : 0.f;
    if (n < NN) {
      int o = t * (NN * 128) + n * 128 + d;
      out[O_H0 + o] = x1;
      out[O_C0 + o] = c0;
    }
  }
}

// ---------------------------------------------------------------------------
// layer 1: X1[N,128] (f32 from out O_H0, packed to bf16 in-register) @ W1T (bf16)
// via mfma_f32_16x16x32_bf16, 3 gates fused + LSTM elementwise + fused
// fin = relu_h1 @ linW + linb. Block: 64 rows, 4 waves; wave w owns d-slice
// [32w,32w+32) for all 3 gates -> (i,cand,o) per (n,d) in same lane.
// A-frag: lane = A[m=lane&15][k=quad*8+j]; B-frag: lane = B[k=quad*8+j][n=lane&15]
// C/D   : col=lane&15, row=quad*4+reg  (m89-verified layout)
// ---------------------------------------------------------------------------
__global__ __launch_bounds__(256) void layer1_kernel(
    float* __restrict__ out, const bf* __restrict__ W1T, const bf* __restrict__ linWT,
    const float* __restrict__ bias1, const float* __restrict__ linb) {
  const int t = blockIdx.y;
  const int n0 = blockIdx.x * 64;
  const int tid = threadIdx.x;
  const int lane = tid & 63, w = tid >> 6;
  const int quad = lane >> 4, l16 = lane & 15;
  const int d0 = w * 32;
  const float* __restrict__ X = out + (size_t)t * NN * 128;   // O_H0 region (f32)
  const short* __restrict__ WT = reinterpret_cast<const short*>(W1T);

  f32x4 acc[4][2][3];
#pragma unroll
  for (int rt = 0; rt < 4; ++rt)
#pragma unroll
    for (int ct = 0; ct < 2; ++ct)
#pragma unroll
      for (int g3 = 0; g3 < 3; ++g3)
        acc[rt][ct][g3] = (f32x4){0.f, 0.f, 0.f, 0.f};

#pragma unroll
  for (int kc = 0; kc < 4; ++kc) {
    const int kofs = kc * 32 + quad * 8;
    short8 a[4];
#pragma unroll
    for (int rt = 0; rt < 4; ++rt) {
      int n = n0 + rt * 16 + l16;
      if (n >= NN) n = NN - 1;          // clamp OOB rows (results unstored)
      f32x4 p0 = *reinterpret_cast<const f32x4*>(X + n * 128 + kofs);
      f32x4 p1 = *reinterpret_cast<const f32x4*>(X + n * 128 + kofs + 4);
#pragma unroll
      for (int j = 0; j < 4; ++j) { a[rt][j] = f2bs(p0[j]); a[rt][4 + j] = f2bs(p1[j]); }
    }
    short8 bfr[3][2];
#pragma unroll
    for (int g3 = 0; g3 < 3; ++g3)
#pragma unroll
      for (int ct = 0; ct < 2; ++ct) {
        int d = d0 + ct * 16 + l16;
        bfr[g3][ct] = *reinterpret_cast<const short8*>(WT + ((t * 3 + g3) * 128 + d) * 128 + kofs);
      }
#pragma unroll
    for (int rt = 0; rt < 4; ++rt)
#pragma unroll
      for (int ct = 0; ct < 2; ++ct)
#pragma unroll
        for (int g3 = 0; g3 < 3; ++g3)
          acc[rt][ct][g3] = __builtin_amdgcn_mfma_f32_16x16x32_bf16(
              a[rt], bfr[g3][ct], acc[rt][ct][g3], 0, 0, 0);
  }

  __shared__ short x2s[64][136];  // +8 pad: rows 16B-aligned, <=2-way bank alias
  float bia[2][3];
#pragma unroll
  for (int ct = 0; ct < 2; ++ct)
#pragma unroll
    for (int g3 = 0; g3 < 3; ++g3)
      bia[ct][g3] = bias1[(t * 3 + g3) * 128 + d0 + ct * 16 + l16];

#pragma unroll
  for (int rt = 0; rt < 4; ++rt)
#pragma unroll
    for (int ct = 0; ct < 2; ++ct) {
      const int dl = d0 + ct * 16 + l16;
#pragma unroll
      for (int reg = 0; reg < 4; ++reg) {
        int nl = rt * 16 + quad * 4 + reg;
        int n = n0 + nl;
        float gi = acc[rt][ct][0][reg] + bia[ct][0];
        float gc = acc[rt][ct][1][reg] + bia[ct][1];
        float go = acc[rt][ct][2][reg] + bia[ct][2];
        float ii = sigm(gi), tt = tanhr(gc), oo = sigm(go);
        float c1 = ii * tt;
        float h = oo * tanhr(c1);
        float x2 = h > 0.f ? h : 0.f;
        x2s[nl][dl] = f2bs(x2);
        if (n < NN) {
          int o = t * (NN * 128) + n * 128 + dl;
          out[O_C1 + o] = c1;
          out[O_H1 + o] = x2;
        }
      }
    }
  __syncthreads();

  // fin: wave w does rows [n0+16w, n0+16w+16) x 16 cols, K=128 from LDS x2
  f32x4 fa = (f32x4){0.f, 0.f, 0.f, 0.f};
#pragma unroll
  for (int kc = 0; kc < 4; ++kc) {
    int kofs = kc * 32 + quad * 8;
    short8 ax = *reinterpret_cast<const short8*>(&x2s[w * 16 + l16][kofs]);
    short8 bx = *reinterpret_cast<const short8*>(
        reinterpret_cast<const short*>(linWT) + (t * 16 + l16) * 128 + kofs);
    fa = __builtin_amdgcn_mfma_f32_16x16x32_bf16(ax, bx, fa, 0, 0, 0);
  }
  float lb = linb[t * 16 + l16];
#pragma unroll
  for (int reg = 0; reg < 4; ++reg) {
    int n = n0 + w * 16 + quad * 4 + reg;
    if (n < NN) out[O_FIN + t * (NN * 16) + n * 16 + l16] = fa[reg] + lb;
  }
}

extern "C" void kernel_launch(void* const* d_in, const int* in_sizes, int n_in,
                              void* d_out, int out_size, void* d_ws, size_t ws_size,
                              hipStream_t stream) {
  // Defensive size-based remap (element counts; all needed sizes unique).
  int iXs = 0, iXg = 1, iW0 = 5, iW1 = 6, iB = 7, iCbl = 9, iLw = 11, iLb = 12;
  int seen_x = 0;
  for (int i = 0; i < n_in; ++i) {
    int s = in_sizes[i];
    if (s == 800000) { if (seen_x == 0) iXs = i; else if (seen_x == 1) iXg = i; ++seen_x; }
    else if (s == 16384)  iW0 = i;
    else if (s == 131072) iW1 = i;
    else if (s == 2048)   iB = i;
    else if (s == 3072)   iCbl = i;
    else if (s == 4096)   iLw = i;
    else if (s == 32)     iLb = i;
  }
  const float* x_st = (const float*)d_in[iXs];
  const float* x_gr = (const float*)d_in[iXg];
  // edge indices (int32) are dead: h,c re-zeroed per layer -> SAGE convs = bias broadcast
  const float* W0   = (const float*)d_in[iW0];
  const float* W1   = (const float*)d_in[iW1];
  const float* b    = (const float*)d_in[iB];
  const float* cbl  = (const float*)d_in[iCbl];   // convWl/convWr dead
  const float* linW = (const float*)d_in[iLw];
  const float* linb = (const float*)d_in[iLb];
  float* out = (float*)d_out;

  char* ws = (char*)d_ws;
  bf* W1T    = (bf*)ws;                 // 196608 B
  bf* linWT  = (bf*)(ws + 196608);      // 8192 B
  float* bias1 = (float*)(ws + 204800); // 3072 B

  prep_kernel<<<403, 256, 0, stream>>>(W1, linW, b, cbl, W1T, linWT, bias1);
  layer0_kernel<<<dim3(1563, 2), 256, 0, stream>>>(x_st, x_gr, W0, b, cbl, out);
  layer1_kernel<<<dim3(782, 2), 256, 0, stream>>>(out, W1T, linWT, bias1, linb);
}

// Round 4
// 293.930 us; speedup vs baseline: 1.0747x; 1.0747x over previous
//
#include <hip/hip_runtime.h>
#include <hip/hip_bf16.h>

// Problem constants
#define NN 50000
#define DD 128
#define FF 16

typedef __hip_bfloat16 bf;
typedef __attribute__((ext_vector_type(8))) short short8;
typedef __attribute__((ext_vector_type(4))) float f32x4;

// Output element offsets (f32 elements, concatenated in reference return order)
#define O_H0  0            // h_lst[0][0], h_lst[0][1]  : 2 * N*128
#define O_H1  12800000     // h_lst[1][0], h_lst[1][1]  : 2 * N*128
#define O_FIN 25600000     // fin[0], fin[1]            : 2 * N*16
#define O_C0  27200000     // c_lst[0][0], c_lst[0][1]  : 2 * N*128
#define O_C1  40000000     // c_lst[1][0], c_lst[1][1]  : 2 * N*128
// total = 52800000 f32 elements

__device__ __forceinline__ bf f2b(float v) { return __float2bfloat16(v); }
__device__ __forceinline__ short f2bs(float v) {
  union { bf h; short s; } u; u.h = __float2bfloat16(v); return u.s;
}
__device__ __forceinline__ float frcp(float x) { return __builtin_amdgcn_rcpf(x); }
__device__ __forceinline__ float sigm(float x) { return frcp(1.f + __expf(-x)); }
__device__ __forceinline__ float tanhr(float x) {
  float e = __expf(2.f * x);
  return (e - 1.f) * frcp(e + 1.f);
}

// ---------------------------------------------------------------------------
// prep: W1 (f32) -> W1T[t][g3][d][k] (bf16), linW (f32) -> linWT[t][j][k] (bf16),
// bias1[t][g3][d] (f32). Gates used: g3 0->i(0), 1->cand(2), 2->o(3); f-gate dead
// because c_prev == 0 (reference re-zeroes state each layer).
// ---------------------------------------------------------------------------
__global__ void prep_kernel(const float* __restrict__ W1, const float* __restrict__ linW,
                            const float* __restrict__ b, const float* __restrict__ cbl,
                            bf* __restrict__ W1T, bf* __restrict__ linWT,
                            float* __restrict__ bias1) {
  int idx = blockIdx.x * 256 + threadIdx.x;
  const int G[3] = {0, 2, 3};
  if (idx < 98304) {                       // W1T: 2*3*128*128
    int t = idx / 49152, r = idx % 49152;
    int g3 = r / 16384, r2 = r % 16384;
    int d = r2 / 128, k = r2 % 128;
    int g = G[g3];
    W1T[idx] = f2b(W1[((g * 2 + t) * 128 + k) * 128 + d]);
  } else if (idx < 102400) {               // linWT: 2*16*128
    int i = idx - 98304;
    int t = i / 2048, r = i % 2048;
    int j = r / 128, k = r % 128;
    linWT[i] = f2b(linW[(t * 128 + k) * 16 + j]);
  } else if (idx < 103168) {               // bias1: 2*3*128 (layer-1 effective bias)
    int i = idx - 102400;
    int t = i / 384, r = i % 384;
    int g3 = r / 128, d = r % 128;
    int g = G[g3];
    // b[l=1][g][t][d] + convbl[l=1]: station (t=0) gets e=1 (g->s);
    // grid (t=1) gets e=0 (s->g) + e=2 (g->g)  [SAGE with h=0 -> its bias]
    float v = b[((4 + g) * 2 + t) * 128 + d];
    if (t == 0) v += cbl[((4 + g) * 3 + 1) * 128 + d];
    else        v += cbl[((4 + g) * 3 + 0) * 128 + d] + cbl[((4 + g) * 3 + 2) * 128 + d];
    bias1[i] = v;
  }
}

// ---------------------------------------------------------------------------
// fused: per block = 64 nodes of one node-type.
//   Phase A: stage x rows (f32, LDS) + W0 (f32, LDS) + layer-0 bias (LDS)
//   Phase B: layer-0 VALU: thread owns column d, 32 nodes; writes h0/c0 (f32,
//            global) and x1 (bf16) straight into the LDS A-tile -> NO HBM
//            round-trip for h0 between layers.
//   Phase C: layer-1 MFMA (3 gates, wave owns d-slice [32w,32w+32)), A from LDS.
//   Phase D: LSTM epilogue in-register, writes h1/c1 (global) + x2 (bf16) into
//            the SAME LDS tile (aliased; sync-separated), then fin MFMA.
// MFMA frags (mfma_f32_16x16x32_bf16): A lane=A[m=lane&15][k=quad*8+j];
// B lane=B[k=quad*8+j][n=lane&15]; C/D col=lane&15,row=quad*4+reg (m89-verified).
// LDS: 4 + 24 + 1.5 + 17.4 = 47.6 KB -> 3 blocks/CU.
// ---------------------------------------------------------------------------
__global__ __launch_bounds__(256) void fused_kernel(
    const float* __restrict__ x_st, const float* __restrict__ x_gr,
    const float* __restrict__ W0, const float* __restrict__ b,
    const float* __restrict__ cbl,
    const bf* __restrict__ W1T, const bf* __restrict__ linWT,
    const float* __restrict__ bias1, const float* __restrict__ linb,
    float* __restrict__ out) {
  const int t = blockIdx.y;
  const int n0 = blockIdx.x * 64;
  const int tid = threadIdx.x;
  const int G[3] = {0, 2, 3};

  __shared__ __align__(16) float sx[64][16];     // 4 KB   (x rows, f32)
  __shared__ float sw[3][16][128];               // 24 KB  (W0 slices, f32)
  __shared__ float sb[3][128];                   // 1.5 KB (layer-0 bias)
  __shared__ __align__(16) short xs[64][136];    // 17.4 KB (x1 bf16; reused for x2)

  // ---- Phase A: stage ----
  {
    const float* __restrict__ x = t ? x_gr : x_st;
    int node = n0 + (tid >> 2);
    int col = (tid & 3) * 4;
    f32x4 v = (f32x4){0.f, 0.f, 0.f, 0.f};
    if (node < NN) v = *reinterpret_cast<const f32x4*>(x + node * 16 + col);
    *reinterpret_cast<f32x4*>(&sx[tid >> 2][col]) = v;
  }
  for (int i = tid; i < 6144; i += 256) {
    int g3 = i >> 11, k = (i >> 7) & 15, d = i & 127;
    sw[g3][k][d] = W0[((G[g3] * 2 + t) * 16 + k) * 128 + d];
  }
  for (int i = tid; i < 384; i += 256) {
    int g3 = i >> 7, d = i & 127, g = G[g3];
    float v = b[(g * 2 + t) * 128 + d];
    v += (t == 0) ? cbl[(g * 3 + 1) * 128 + d]
                  : cbl[(g * 3 + 0) * 128 + d] + cbl[(g * 3 + 2) * 128 + d];
    sb[g3][d] = v;
  }
  __syncthreads();

  // ---- Phase B: layer 0 ----
  {
    const int d = tid & 127, half = tid >> 7;
    float w0r[16], w2r[16], w3r[16];
#pragma unroll
    for (int k = 0; k < 16; ++k) {
      w0r[k] = sw[0][k][d]; w2r[k] = sw[1][k][d]; w3r[k] = sw[2][k][d];
    }
    const float b0 = sb[0][d], b2v = sb[1][d], b3 = sb[2][d];
    for (int j = 0; j < 32; ++j) {
      int nl = half * 32 + j;
      int n = n0 + nl;
      float a0 = b0, a2 = b2v, a3 = b3;
#pragma unroll
      for (int k = 0; k < 16; ++k) {
        float xv = sx[nl][k];
        a0 += xv * w0r[k]; a2 += xv * w2r[k]; a3 += xv * w3r[k];
      }
      float ii = sigm(a0), tt = tanhr(a2), oo = sigm(a3);
      float c0 = ii * tt;
      float h = oo * tanhr(c0);
      float x1 = h > 0.f ? h : 0.f;
      xs[nl][d] = f2bs(x1);
      if (n < NN) {
        int o = t * (NN * 128) + n * 128 + d;
        out[O_H0 + o] = x1;
        out[O_C0 + o] = c0;
      }
    }
  }
  __syncthreads();

  // ---- Phase C: layer 1 MFMA ----
  const int lane = tid & 63, w = tid >> 6;
  const int quad = lane >> 4, l16 = lane & 15;
  const int d0 = w * 32;
  const short* __restrict__ WT = reinterpret_cast<const short*>(W1T);

  f32x4 acc[4][2][3];
#pragma unroll
  for (int rt = 0; rt < 4; ++rt)
#pragma unroll
    for (int ct = 0; ct < 2; ++ct)
#pragma unroll
      for (int g3 = 0; g3 < 3; ++g3)
        acc[rt][ct][g3] = (f32x4){0.f, 0.f, 0.f, 0.f};

#pragma unroll
  for (int kc = 0; kc < 4; ++kc) {
    const int kofs = kc * 32 + quad * 8;
    short8 a[4];
#pragma unroll
    for (int rt = 0; rt < 4; ++rt)
      a[rt] = *reinterpret_cast<const short8*>(&xs[rt * 16 + l16][kofs]);
    short8 bfr[3][2];
#pragma unroll
    for (int g3 = 0; g3 < 3; ++g3)
#pragma unroll
      for (int ct = 0; ct < 2; ++ct) {
        int d = d0 + ct * 16 + l16;
        bfr[g3][ct] = *reinterpret_cast<const short8*>(WT + ((t * 3 + g3) * 128 + d) * 128 + kofs);
      }
#pragma unroll
    for (int rt = 0; rt < 4; ++rt)
#pragma unroll
      for (int ct = 0; ct < 2; ++ct)
#pragma unroll
        for (int g3 = 0; g3 < 3; ++g3)
          acc[rt][ct][g3] = __builtin_amdgcn_mfma_f32_16x16x32_bf16(
              a[rt], bfr[g3][ct], acc[rt][ct][g3], 0, 0, 0);
  }
  __syncthreads();   // xs reads done; safe to overwrite with x2

  // ---- Phase D: LSTM epilogue + fused fin ----
  float bia[2][3];
#pragma unroll
  for (int ct = 0; ct < 2; ++ct)
#pragma unroll
    for (int g3 = 0; g3 < 3; ++g3)
      bia[ct][g3] = bias1[(t * 3 + g3) * 128 + d0 + ct * 16 + l16];

#pragma unroll
  for (int rt = 0; rt < 4; ++rt)
#pragma unroll
    for (int ct = 0; ct < 2; ++ct) {
      const int dl = d0 + ct * 16 + l16;
#pragma unroll
      for (int reg = 0; reg < 4; ++reg) {
        int nl = rt * 16 + quad * 4 + reg;
        int n = n0 + nl;
        float gi = acc[rt][ct][0][reg] + bia[ct][0];
        float gc = acc[rt][ct][1][reg] + bia[ct][1];
        float go = acc[rt][ct][2][reg] + bia[ct][2];
        float ii = sigm(gi), tt = tanhr(gc), oo = sigm(go);
        float c1 = ii * tt;
        float h = oo * tanhr(c1);
        float x2 = h > 0.f ? h : 0.f;
        xs[nl][dl] = f2bs(x2);
        if (n < NN) {
          int o = t * (NN * 128) + n * 128 + dl;
          out[O_C1 + o] = c1;
          out[O_H1 + o] = x2;
        }
      }
    }
  __syncthreads();

  // fin: wave w does rows [n0+16w, n0+16w+16) x 16 cols, K=128 from LDS x2
  f32x4 fa = (f32x4){0.f, 0.f, 0.f, 0.f};
#pragma unroll
  for (int kc = 0; kc < 4; ++kc) {
    int kofs = kc * 32 + quad * 8;
    short8 ax = *reinterpret_cast<const short8*>(&xs[w * 16 + l16][kofs]);
    short8 bx = *reinterpret_cast<const short8*>(
        reinterpret_cast<const short*>(linWT) + (t * 16 + l16) * 128 + kofs);
    fa = __builtin_amdgcn_mfma_f32_16x16x32_bf16(ax, bx, fa, 0, 0, 0);
  }
  float lb = linb[t * 16 + l16];
#pragma unroll
  for (int reg = 0; reg < 4; ++reg) {
    int n = n0 + w * 16 + quad * 4 + reg;
    if (n < NN) out[O_FIN + t * (NN * 16) + n * 16 + l16] = fa[reg] + lb;
  }
}

extern "C" void kernel_launch(void* const* d_in, const int* in_sizes, int n_in,
                              void* d_out, int out_size, void* d_ws, size_t ws_size,
                              hipStream_t stream) {
  // Defensive size-based remap (element counts; all needed sizes unique).
  int iXs = 0, iXg = 1, iW0 = 5, iW1 = 6, iB = 7, iCbl = 9, iLw = 11, iLb = 12;
  int seen_x = 0;
  for (int i = 0; i < n_in; ++i) {
    int s = in_sizes[i];
    if (s == 800000) { if (seen_x == 0) iXs = i; else if (seen_x == 1) iXg = i; ++seen_x; }
    else if (s == 16384)  iW0 = i;
    else if (s == 131072) iW1 = i;
    else if (s == 2048)   iB = i;
    else if (s == 3072)   iCbl = i;
    else if (s == 4096)   iLw = i;
    else if (s == 32)     iLb = i;
  }
  const float* x_st = (const float*)d_in[iXs];
  const float* x_gr = (const float*)d_in[iXg];
  // edge indices (int32) are dead: h,c re-zeroed per layer -> SAGE convs = bias broadcast
  const float* W0   = (const float*)d_in[iW0];
  const float* W1   = (const float*)d_in[iW1];
  const float* b    = (const float*)d_in[iB];
  const float* cbl  = (const float*)d_in[iCbl];   // convWl/convWr dead
  const float* linW = (const float*)d_in[iLw];
  const float* linb = (const float*)d_in[iLb];
  float* out = (float*)d_out;

  char* ws = (char*)d_ws;
  bf* W1T    = (bf*)ws;                 // 196608 B
  bf* linWT  = (bf*)(ws + 196608);      // 8192 B
  float* bias1 = (float*)(ws + 204800); // 3072 B

  prep_kernel<<<403, 256, 0, stream>>>(W1, linW, b, cbl, W1T, linWT, bias1);
  fused_kernel<<<dim3(782, 2), 256, 0, stream>>>(x_st, x_gr, W0, b, cbl,
                                                 W1T, linWT, bias1, linb, out);
}